// Round 11
// baseline (80.534 us; speedup 1.0000x reference)
//
#include <hip/hip_runtime.h>

// DropBlock, N=64 C=64 H=80 W=80, block_size=5 (top/left-clipped window max).
// R11 = R7 base (best, 65.1us) with:
//  (a) software-pipelined mask phase 1: burst c+1's 10 loads issue into a
//      second reg array BEFORE burst c's ballots consume theirs (kills the
//      per-burst vmcnt bubble; v/w double-buffer, outer unroll 1).
//  (b) INSTRUMENTATION: mask kernel launched TWICE (idempotent — identical
//      bits/counts). dur_us = base + mask_dur + ~2us launch; next round drops
//      the dup to decompose mask vs apply from the two totals.
// Lessons kept: no atomics (R3), no memset in graph (R4), no grid.sync (R8).
#define DB_H 80
#define DB_W 80
#define DB_PLANE (DB_H * DB_W)               // 6400
#define DB_NPLANES 4096                      // N*C
#define DB_ROW_WORDS 3                       // 96-bit padded row of block mask
#define DB_PLANE_WORDS (DB_H * DB_ROW_WORDS) // 240
#define DB_TOTAL (DB_PLANE * DB_NPLANES)     // 26214400
#define DB_COUNT_F 26214400.0f               // 25 * 2^20 — exact in f32
#define DB_CNT_BYTES (DB_NPLANES * 4)        // 16384
#define PPBLK 2                              // planes per block (2 waves each)
#define WPB 4                                // fallback kernels only

// Kernel 1: per-plane bitboard window-OR + zero count + packed mask store.
// Block = 4 waves = 2 planes; each wave owns one half (50 qwords / 40 rows).
__global__ __launch_bounds__(256) void db_mask_kernel(
    const int* __restrict__ mask,
    unsigned int* __restrict__ bits,
    unsigned int* __restrict__ counts)
{
    __shared__ unsigned long long P[PPBLK][104];        // packed seed bits
    __shared__ unsigned int RO[PPBLK][DB_PLANE_WORDS];  // row-OR, 3 words/row
    __shared__ unsigned int ZP[PPBLK][2];               // zero partials
    const int t = threadIdx.x;
    const int wid = t >> 6, lane = t & 63;
    const int pib = wid >> 1, half = wid & 1;
    const int plane = blockIdx.x * PPBLK + pib;
    const int* mp = mask + plane * DB_PLANE;
    unsigned long long* Pp = P[pib];
    unsigned int* ro = RO[pib];

    // Phase 1 (software-pipelined): wave packs qwords [half*50, half*50+50).
    // Burst c+1's loads are issued before burst c's ballots consume v[].
    {
        const int base0 = half * 50;
        int v[10], w[10];
        #pragma unroll
        for (int k = 0; k < 10; ++k) v[k] = mp[(base0 + k) * 64 + lane];
        #pragma unroll 1
        for (int c = 0; c < 5; ++c) {
            const int base = base0 + c * 10;
            if (c < 4) {
                #pragma unroll
                for (int k = 0; k < 10; ++k)
                    w[k] = mp[(base + 10 + k) * 64 + lane];
            }
            #pragma unroll
            for (int k = 0; k < 10; ++k) {
                unsigned long long bal = __ballot(v[k] & 1);
                if (lane == 0) Pp[base + k] = bal;
            }
            #pragma unroll
            for (int k = 0; k < 10; ++k) v[k] = w[k];
        }
    }
    if (t < 2 * 4) P[t >> 2][100 + (t & 3)] = 0ULL;   // zero pad both planes
    __syncthreads();

    // Phase 2: row sliding-OR (width 5, left-clipped) for rows
    // [half*40, half*40+40). Row = 80 bits as 128-bit (b:a).
    if (lane < 40) {
        const int r = half * 40 + lane;
        const int bitpos = r * DB_W;
        const int q = bitpos >> 6, off = bitpos & 63;
        unsigned long long a, b;
        if (off) {
            a = (Pp[q] >> off) | (Pp[q + 1] << (64 - off));
            b = (Pp[q + 1] >> off) | (Pp[q + 2] << (64 - off));
        } else {
            a = Pp[q]; b = Pp[q + 1];
        }
        b &= 0xFFFFULL;
        unsigned long long ra = a, rb = b;
        #pragma unroll
        for (int s = 1; s <= 4; ++s) {
            ra |= a << s;
            rb |= (b << s) | (a >> (64 - s));
        }
        rb &= 0xFFFFULL;
        ro[r * 3 + 0] = (unsigned int)ra;
        ro[r * 3 + 1] = (unsigned int)(ra >> 32);
        ro[r * 3 + 2] = (unsigned int)rb;
    }
    __syncthreads();

    // Phase 3: col OR over rows i-4..i (top clip), count zeros, store bits.
    unsigned int zeros = 0;
    if (lane < 40) {
        const int i = half * 40 + lane;
        const int lo = (i >= 4) ? i - 4 : 0;
        unsigned int c0 = 0, c1 = 0, c2 = 0;
        for (int ii = lo; ii <= i; ++ii) {
            c0 |= ro[ii * 3 + 0];
            c1 |= ro[ii * 3 + 1];
            c2 |= ro[ii * 3 + 2];
        }
        zeros = 80u - __popc(c0) - __popc(c1) - __popc(c2);
        unsigned int* bp = bits + plane * DB_PLANE_WORDS + i * 3;
        bp[0] = c0; bp[1] = c1; bp[2] = c2;
    }
    for (int off = 32; off > 0; off >>= 1)
        zeros += (unsigned int)__shfl_down((int)zeros, off, 64);
    if (lane == 0) ZP[pib][half] = zeros;
    __syncthreads();
    if (lane == 0 && half == 0)
        counts[plane] = ZP[pib][0] + ZP[pib][1];   // plain store, no init
}

// Kernel 2: out = blocked ? 0 : x * (countM / count_zeros), float4 stream.
// Prologue: block-local sum of the 4096 per-plane counts (L3-hit, 16KB).
__global__ __launch_bounds__(256) void db_apply_bits(
    const float4* __restrict__ x,
    const unsigned int* __restrict__ bits,
    const unsigned int* __restrict__ counts,
    float4* __restrict__ out)
{
    __shared__ float s_scale;
    __shared__ unsigned int s_part[4];
    {
        const uint4* cp = (const uint4*)counts;   // 1024 uint4
        unsigned int c = 0;
        #pragma unroll
        for (int k = 0; k < 4; ++k) {
            uint4 v = cp[k * 256 + threadIdx.x];
            c += v.x + v.y + v.z + v.w;
        }
        for (int off = 32; off > 0; off >>= 1)
            c += (unsigned int)__shfl_down((int)c, off, 64);
        if ((threadIdx.x & 63) == 0) s_part[threadIdx.x >> 6] = c;
        __syncthreads();
        if (threadIdx.x == 0)
            s_scale = DB_COUNT_F /
                      (float)(s_part[0] + s_part[1] + s_part[2] + s_part[3]);
        __syncthreads();
    }
    const float scale = s_scale;
    const int NG = DB_TOTAL / 4;
    const int stride = gridDim.x * blockDim.x;
    #pragma unroll 2
    for (int g = blockIdx.x * blockDim.x + threadIdx.x; g < NG; g += stride) {
        int e = g * 4;
        int plane = e / DB_PLANE;
        int ep = e - plane * DB_PLANE;
        int i = ep / DB_W;
        int j = ep - i * DB_W;   // j % 4 == 0; 4 bits never cross a word
        unsigned int nib =
            (bits[plane * DB_PLANE_WORDS + i * 3 + (j >> 5)] >> (j & 31)) & 0xFu;
        float4 v = make_float4(0.f, 0.f, 0.f, 0.f);
        if (nib != 0xFu) v = x[g];
        float4 o;
        o.x = (nib & 1u) ? 0.0f : v.x * scale;
        o.y = (nib & 2u) ? 0.0f : v.y * scale;
        o.z = (nib & 4u) ? 0.0f : v.z * scale;
        o.w = (nib & 8u) ? 0.0f : v.w * scale;
        out[g] = o;
    }
}

// ---- Fallback path (ws too small for bits) — R7 recompute, known-good. ----
__global__ __launch_bounds__(256) void db_count_kernel(
    const int* __restrict__ mask,
    unsigned int* __restrict__ counts)
{
    __shared__ unsigned long long P[WPB][104];
    __shared__ unsigned int RO[WPB][DB_PLANE_WORDS];
    const int wid = threadIdx.x >> 6, lane = threadIdx.x & 63;
    const int plane = blockIdx.x * WPB + wid;
    const int* mp = mask + plane * DB_PLANE;
    unsigned long long* Pp = P[wid];
    unsigned int* ro = RO[wid];
    #pragma unroll 1
    for (int c = 0; c < 10; ++c) {
        int v[10];
        #pragma unroll
        for (int k = 0; k < 10; ++k) v[k] = mp[(c * 10 + k) * 64 + lane];
        #pragma unroll
        for (int k = 0; k < 10; ++k) {
            unsigned long long bal = __ballot(v[k] & 1);
            if (lane == 0) Pp[c * 10 + k] = bal;
        }
    }
    if (lane < 4) Pp[100 + lane] = 0ULL;
    __syncthreads();
    for (int r = lane; r < DB_H; r += 64) {
        const int bitpos = r * DB_W;
        const int q = bitpos >> 6, off = bitpos & 63;
        unsigned long long a, b;
        if (off) {
            a = (Pp[q] >> off) | (Pp[q + 1] << (64 - off));
            b = (Pp[q + 1] >> off) | (Pp[q + 2] << (64 - off));
        } else {
            a = Pp[q]; b = Pp[q + 1];
        }
        b &= 0xFFFFULL;
        unsigned long long ra = a, rb = b;
        #pragma unroll
        for (int s = 1; s <= 4; ++s) {
            ra |= a << s;
            rb |= (b << s) | (a >> (64 - s));
        }
        rb &= 0xFFFFULL;
        ro[r * 3 + 0] = (unsigned int)ra;
        ro[r * 3 + 1] = (unsigned int)(ra >> 32);
        ro[r * 3 + 2] = (unsigned int)rb;
    }
    __syncthreads();
    unsigned int zeros = 0;
    for (int i = lane; i < DB_H; i += 64) {
        const int lo = (i >= 4) ? i - 4 : 0;
        unsigned int c0 = 0, c1 = 0, c2 = 0;
        for (int ii = lo; ii <= i; ++ii) {
            c0 |= ro[ii * 3 + 0];
            c1 |= ro[ii * 3 + 1];
            c2 |= ro[ii * 3 + 2];
        }
        zeros += 80u - __popc(c0) - __popc(c1) - __popc(c2);
    }
    for (int off = 32; off > 0; off >>= 1)
        zeros += (unsigned int)__shfl_down((int)zeros, off, 64);
    if (lane == 0) counts[plane] = zeros;
}

__global__ __launch_bounds__(256) void db_apply_recompute(
    const float* __restrict__ x,
    const int* __restrict__ mask,
    const unsigned int* __restrict__ counts,
    float* __restrict__ out)
{
    __shared__ unsigned long long P[WPB][104];
    __shared__ unsigned int RO[WPB][DB_PLANE_WORDS];
    __shared__ unsigned int BM[WPB][DB_PLANE_WORDS];
    __shared__ float s_scale;
    __shared__ unsigned int s_part[4];
    {
        const uint4* cp = (const uint4*)counts;
        unsigned int c = 0;
        #pragma unroll
        for (int k = 0; k < 4; ++k) {
            uint4 v = cp[k * 256 + threadIdx.x];
            c += v.x + v.y + v.z + v.w;
        }
        for (int off = 32; off > 0; off >>= 1)
            c += (unsigned int)__shfl_down((int)c, off, 64);
        if ((threadIdx.x & 63) == 0) s_part[threadIdx.x >> 6] = c;
        __syncthreads();
        if (threadIdx.x == 0)
            s_scale = DB_COUNT_F /
                      (float)(s_part[0] + s_part[1] + s_part[2] + s_part[3]);
        __syncthreads();
    }
    const float scale = s_scale;
    const int wid = threadIdx.x >> 6, lane = threadIdx.x & 63;
    const int plane = blockIdx.x * WPB + wid;
    const int* mp = mask + plane * DB_PLANE;
    unsigned long long* Pp = P[wid];
    unsigned int* ro = RO[wid];
    #pragma unroll 1
    for (int c = 0; c < 10; ++c) {
        int v[10];
        #pragma unroll
        for (int k = 0; k < 10; ++k) v[k] = mp[(c * 10 + k) * 64 + lane];
        #pragma unroll
        for (int k = 0; k < 10; ++k) {
            unsigned long long bal = __ballot(v[k] & 1);
            if (lane == 0) Pp[c * 10 + k] = bal;
        }
    }
    if (lane < 4) Pp[100 + lane] = 0ULL;
    __syncthreads();
    for (int r = lane; r < DB_H; r += 64) {
        const int bitpos = r * DB_W;
        const int q = bitpos >> 6, off = bitpos & 63;
        unsigned long long a, b;
        if (off) {
            a = (Pp[q] >> off) | (Pp[q + 1] << (64 - off));
            b = (Pp[q + 1] >> off) | (Pp[q + 2] << (64 - off));
        } else {
            a = Pp[q]; b = Pp[q + 1];
        }
        b &= 0xFFFFULL;
        unsigned long long ra = a, rb = b;
        #pragma unroll
        for (int s = 1; s <= 4; ++s) {
            ra |= a << s;
            rb |= (b << s) | (a >> (64 - s));
        }
        rb &= 0xFFFFULL;
        ro[r * 3 + 0] = (unsigned int)ra;
        ro[r * 3 + 1] = (unsigned int)(ra >> 32);
        ro[r * 3 + 2] = (unsigned int)rb;
    }
    __syncthreads();
    unsigned int* bmp = BM[wid];
    for (int i = lane; i < DB_H; i += 64) {
        const int lo = (i >= 4) ? i - 4 : 0;
        unsigned int c0 = 0, c1 = 0, c2 = 0;
        for (int ii = lo; ii <= i; ++ii) {
            c0 |= ro[ii * 3 + 0];
            c1 |= ro[ii * 3 + 1];
            c2 |= ro[ii * 3 + 2];
        }
        bmp[i * 3 + 0] = c0; bmp[i * 3 + 1] = c1; bmp[i * 3 + 2] = c2;
    }
    __syncthreads();
    const float* xp = x + plane * DB_PLANE;
    float* op = out + plane * DB_PLANE;
    for (int e = lane; e < DB_PLANE; e += 64) {
        int i = e / DB_W, j = e - i * DB_W;
        unsigned int wb = bmp[i * 3 + (j >> 5)] >> (j & 31);
        op[e] = (wb & 1u) ? 0.0f : xp[e] * scale;
    }
}

extern "C" void kernel_launch(void* const* d_in, const int* in_sizes, int n_in,
                              void* d_out, int out_size, void* d_ws, size_t ws_size,
                              hipStream_t stream) {
    const float* x = (const float*)d_in[0];
    const int* mask = (const int*)d_in[1];
    float* out = (float*)d_out;

    unsigned int* counts = (unsigned int*)d_ws;
    unsigned int* bits = (unsigned int*)((char*)d_ws + DB_CNT_BYTES);
    const size_t bits_bytes = (size_t)DB_NPLANES * DB_PLANE_WORDS * 4;
    const bool use_bits = ws_size >= DB_CNT_BYTES + bits_bytes;

    if (use_bits) {
        // INSTRUMENTATION (this round only): mask launched twice, idempotent.
        // dur_us = base + mask_dur + ~2us; next round removes the dup.
        db_mask_kernel<<<DB_NPLANES / PPBLK, 256, 0, stream>>>(mask, bits,
                                                               counts);
        db_mask_kernel<<<DB_NPLANES / PPBLK, 256, 0, stream>>>(mask, bits,
                                                               counts);
        db_apply_bits<<<2048, 256, 0, stream>>>(
            (const float4*)x, bits, counts, (float4*)out);
    } else {
        db_count_kernel<<<DB_NPLANES / WPB, 256, 0, stream>>>(mask, counts);
        db_apply_recompute<<<DB_NPLANES / WPB, 256, 0, stream>>>(
            x, mask, counts, out);
    }
}

// Round 12
// 65.354 us; speedup vs baseline: 1.2323x; 1.2323x over previous
//
#include <hip/hip_runtime.h>

// DropBlock, N=64 C=64 H=80 W=80, block_size=5 (top/left-clipped window max).
// R12 = R11 minus the instrumentation dup. Final structure:
//   K1 db_mask_kernel: ballot bitboard pack with software-pipelined loads
//      (v/w double-buffer: burst c+1's 10 loads in flight over burst c's
//      ballots), 128-bit row sliding-OR, 5-row col OR, packed bits + counts.
//      Measured ~13.5us L3-hot / ~19us cold (R11 dup-launch decomposition).
//   K2 db_apply_bits: counts-sum prologue (16KB, L3), float4 stream apply
//      with predicated x-load skip. ~34us at 210MB (roofline).
// Lessons: no atomics (R3: 20ns/ea serialized), no memset in graph (R4:
// ~60us/replay), no cooperative grid.sync (R8: ~400us), pipeline the load
// bursts (R11: -8..10us), redistribute/bitplane/scatter variants all
// plateau >= this structure (R7/R9/R10).
#define DB_H 80
#define DB_W 80
#define DB_PLANE (DB_H * DB_W)               // 6400
#define DB_NPLANES 4096                      // N*C
#define DB_ROW_WORDS 3                       // 96-bit padded row of block mask
#define DB_PLANE_WORDS (DB_H * DB_ROW_WORDS) // 240
#define DB_TOTAL (DB_PLANE * DB_NPLANES)     // 26214400
#define DB_COUNT_F 26214400.0f               // 25 * 2^20 — exact in f32
#define DB_CNT_BYTES (DB_NPLANES * 4)        // 16384
#define PPBLK 2                              // planes per block (2 waves each)
#define WPB 4                                // fallback kernels only

// Kernel 1: per-plane bitboard window-OR + zero count + packed mask store.
// Block = 4 waves = 2 planes; each wave owns one half (50 qwords / 40 rows).
__global__ __launch_bounds__(256) void db_mask_kernel(
    const int* __restrict__ mask,
    unsigned int* __restrict__ bits,
    unsigned int* __restrict__ counts)
{
    __shared__ unsigned long long P[PPBLK][104];        // packed seed bits
    __shared__ unsigned int RO[PPBLK][DB_PLANE_WORDS];  // row-OR, 3 words/row
    __shared__ unsigned int ZP[PPBLK][2];               // zero partials
    const int t = threadIdx.x;
    const int wid = t >> 6, lane = t & 63;
    const int pib = wid >> 1, half = wid & 1;
    const int plane = blockIdx.x * PPBLK + pib;
    const int* mp = mask + plane * DB_PLANE;
    unsigned long long* Pp = P[pib];
    unsigned int* ro = RO[pib];

    // Phase 1 (software-pipelined): wave packs qwords [half*50, half*50+50).
    // Burst c+1's loads are issued before burst c's ballots consume v[].
    {
        const int base0 = half * 50;
        int v[10], w[10];
        #pragma unroll
        for (int k = 0; k < 10; ++k) v[k] = mp[(base0 + k) * 64 + lane];
        #pragma unroll 1
        for (int c = 0; c < 5; ++c) {
            const int base = base0 + c * 10;
            if (c < 4) {
                #pragma unroll
                for (int k = 0; k < 10; ++k)
                    w[k] = mp[(base + 10 + k) * 64 + lane];
            }
            #pragma unroll
            for (int k = 0; k < 10; ++k) {
                unsigned long long bal = __ballot(v[k] & 1);
                if (lane == 0) Pp[base + k] = bal;
            }
            #pragma unroll
            for (int k = 0; k < 10; ++k) v[k] = w[k];
        }
    }
    if (t < 2 * 4) P[t >> 2][100 + (t & 3)] = 0ULL;   // zero pad both planes
    __syncthreads();

    // Phase 2: row sliding-OR (width 5, left-clipped) for rows
    // [half*40, half*40+40). Row = 80 bits as 128-bit (b:a).
    if (lane < 40) {
        const int r = half * 40 + lane;
        const int bitpos = r * DB_W;
        const int q = bitpos >> 6, off = bitpos & 63;
        unsigned long long a, b;
        if (off) {
            a = (Pp[q] >> off) | (Pp[q + 1] << (64 - off));
            b = (Pp[q + 1] >> off) | (Pp[q + 2] << (64 - off));
        } else {
            a = Pp[q]; b = Pp[q + 1];
        }
        b &= 0xFFFFULL;
        unsigned long long ra = a, rb = b;
        #pragma unroll
        for (int s = 1; s <= 4; ++s) {
            ra |= a << s;
            rb |= (b << s) | (a >> (64 - s));
        }
        rb &= 0xFFFFULL;
        ro[r * 3 + 0] = (unsigned int)ra;
        ro[r * 3 + 1] = (unsigned int)(ra >> 32);
        ro[r * 3 + 2] = (unsigned int)rb;
    }
    __syncthreads();

    // Phase 3: col OR over rows i-4..i (top clip), count zeros, store bits.
    unsigned int zeros = 0;
    if (lane < 40) {
        const int i = half * 40 + lane;
        const int lo = (i >= 4) ? i - 4 : 0;
        unsigned int c0 = 0, c1 = 0, c2 = 0;
        for (int ii = lo; ii <= i; ++ii) {
            c0 |= ro[ii * 3 + 0];
            c1 |= ro[ii * 3 + 1];
            c2 |= ro[ii * 3 + 2];
        }
        zeros = 80u - __popc(c0) - __popc(c1) - __popc(c2);
        unsigned int* bp = bits + plane * DB_PLANE_WORDS + i * 3;
        bp[0] = c0; bp[1] = c1; bp[2] = c2;
    }
    for (int off = 32; off > 0; off >>= 1)
        zeros += (unsigned int)__shfl_down((int)zeros, off, 64);
    if (lane == 0) ZP[pib][half] = zeros;
    __syncthreads();
    if (lane == 0 && half == 0)
        counts[plane] = ZP[pib][0] + ZP[pib][1];   // plain store, no init
}

// Kernel 2: out = blocked ? 0 : x * (countM / count_zeros), float4 stream.
// Prologue: block-local sum of the 4096 per-plane counts (L3-hit, 16KB).
__global__ __launch_bounds__(256) void db_apply_bits(
    const float4* __restrict__ x,
    const unsigned int* __restrict__ bits,
    const unsigned int* __restrict__ counts,
    float4* __restrict__ out)
{
    __shared__ float s_scale;
    __shared__ unsigned int s_part[4];
    {
        const uint4* cp = (const uint4*)counts;   // 1024 uint4
        unsigned int c = 0;
        #pragma unroll
        for (int k = 0; k < 4; ++k) {
            uint4 v = cp[k * 256 + threadIdx.x];
            c += v.x + v.y + v.z + v.w;
        }
        for (int off = 32; off > 0; off >>= 1)
            c += (unsigned int)__shfl_down((int)c, off, 64);
        if ((threadIdx.x & 63) == 0) s_part[threadIdx.x >> 6] = c;
        __syncthreads();
        if (threadIdx.x == 0)
            s_scale = DB_COUNT_F /
                      (float)(s_part[0] + s_part[1] + s_part[2] + s_part[3]);
        __syncthreads();
    }
    const float scale = s_scale;
    const int NG = DB_TOTAL / 4;
    const int stride = gridDim.x * blockDim.x;
    #pragma unroll 2
    for (int g = blockIdx.x * blockDim.x + threadIdx.x; g < NG; g += stride) {
        int e = g * 4;
        int plane = e / DB_PLANE;
        int ep = e - plane * DB_PLANE;
        int i = ep / DB_W;
        int j = ep - i * DB_W;   // j % 4 == 0; 4 bits never cross a word
        unsigned int nib =
            (bits[plane * DB_PLANE_WORDS + i * 3 + (j >> 5)] >> (j & 31)) & 0xFu;
        float4 v = make_float4(0.f, 0.f, 0.f, 0.f);
        if (nib != 0xFu) v = x[g];
        float4 o;
        o.x = (nib & 1u) ? 0.0f : v.x * scale;
        o.y = (nib & 2u) ? 0.0f : v.y * scale;
        o.z = (nib & 4u) ? 0.0f : v.z * scale;
        o.w = (nib & 8u) ? 0.0f : v.w * scale;
        out[g] = o;
    }
}

// ---- Fallback path (ws too small for bits) — R7 recompute, known-good. ----
__global__ __launch_bounds__(256) void db_count_kernel(
    const int* __restrict__ mask,
    unsigned int* __restrict__ counts)
{
    __shared__ unsigned long long P[WPB][104];
    __shared__ unsigned int RO[WPB][DB_PLANE_WORDS];
    const int wid = threadIdx.x >> 6, lane = threadIdx.x & 63;
    const int plane = blockIdx.x * WPB + wid;
    const int* mp = mask + plane * DB_PLANE;
    unsigned long long* Pp = P[wid];
    unsigned int* ro = RO[wid];
    #pragma unroll 1
    for (int c = 0; c < 10; ++c) {
        int v[10];
        #pragma unroll
        for (int k = 0; k < 10; ++k) v[k] = mp[(c * 10 + k) * 64 + lane];
        #pragma unroll
        for (int k = 0; k < 10; ++k) {
            unsigned long long bal = __ballot(v[k] & 1);
            if (lane == 0) Pp[c * 10 + k] = bal;
        }
    }
    if (lane < 4) Pp[100 + lane] = 0ULL;
    __syncthreads();
    for (int r = lane; r < DB_H; r += 64) {
        const int bitpos = r * DB_W;
        const int q = bitpos >> 6, off = bitpos & 63;
        unsigned long long a, b;
        if (off) {
            a = (Pp[q] >> off) | (Pp[q + 1] << (64 - off));
            b = (Pp[q + 1] >> off) | (Pp[q + 2] << (64 - off));
        } else {
            a = Pp[q]; b = Pp[q + 1];
        }
        b &= 0xFFFFULL;
        unsigned long long ra = a, rb = b;
        #pragma unroll
        for (int s = 1; s <= 4; ++s) {
            ra |= a << s;
            rb |= (b << s) | (a >> (64 - s));
        }
        rb &= 0xFFFFULL;
        ro[r * 3 + 0] = (unsigned int)ra;
        ro[r * 3 + 1] = (unsigned int)(ra >> 32);
        ro[r * 3 + 2] = (unsigned int)rb;
    }
    __syncthreads();
    unsigned int zeros = 0;
    for (int i = lane; i < DB_H; i += 64) {
        const int lo = (i >= 4) ? i - 4 : 0;
        unsigned int c0 = 0, c1 = 0, c2 = 0;
        for (int ii = lo; ii <= i; ++ii) {
            c0 |= ro[ii * 3 + 0];
            c1 |= ro[ii * 3 + 1];
            c2 |= ro[ii * 3 + 2];
        }
        zeros += 80u - __popc(c0) - __popc(c1) - __popc(c2);
    }
    for (int off = 32; off > 0; off >>= 1)
        zeros += (unsigned int)__shfl_down((int)zeros, off, 64);
    if (lane == 0) counts[plane] = zeros;
}

__global__ __launch_bounds__(256) void db_apply_recompute(
    const float* __restrict__ x,
    const int* __restrict__ mask,
    const unsigned int* __restrict__ counts,
    float* __restrict__ out)
{
    __shared__ unsigned long long P[WPB][104];
    __shared__ unsigned int RO[WPB][DB_PLANE_WORDS];
    __shared__ unsigned int BM[WPB][DB_PLANE_WORDS];
    __shared__ float s_scale;
    __shared__ unsigned int s_part[4];
    {
        const uint4* cp = (const uint4*)counts;
        unsigned int c = 0;
        #pragma unroll
        for (int k = 0; k < 4; ++k) {
            uint4 v = cp[k * 256 + threadIdx.x];
            c += v.x + v.y + v.z + v.w;
        }
        for (int off = 32; off > 0; off >>= 1)
            c += (unsigned int)__shfl_down((int)c, off, 64);
        if ((threadIdx.x & 63) == 0) s_part[threadIdx.x >> 6] = c;
        __syncthreads();
        if (threadIdx.x == 0)
            s_scale = DB_COUNT_F /
                      (float)(s_part[0] + s_part[1] + s_part[2] + s_part[3]);
        __syncthreads();
    }
    const float scale = s_scale;
    const int wid = threadIdx.x >> 6, lane = threadIdx.x & 63;
    const int plane = blockIdx.x * WPB + wid;
    const int* mp = mask + plane * DB_PLANE;
    unsigned long long* Pp = P[wid];
    unsigned int* ro = RO[wid];
    #pragma unroll 1
    for (int c = 0; c < 10; ++c) {
        int v[10];
        #pragma unroll
        for (int k = 0; k < 10; ++k) v[k] = mp[(c * 10 + k) * 64 + lane];
        #pragma unroll
        for (int k = 0; k < 10; ++k) {
            unsigned long long bal = __ballot(v[k] & 1);
            if (lane == 0) Pp[c * 10 + k] = bal;
        }
    }
    if (lane < 4) Pp[100 + lane] = 0ULL;
    __syncthreads();
    for (int r = lane; r < DB_H; r += 64) {
        const int bitpos = r * DB_W;
        const int q = bitpos >> 6, off = bitpos & 63;
        unsigned long long a, b;
        if (off) {
            a = (Pp[q] >> off) | (Pp[q + 1] << (64 - off));
            b = (Pp[q + 1] >> off) | (Pp[q + 2] << (64 - off));
        } else {
            a = Pp[q]; b = Pp[q + 1];
        }
        b &= 0xFFFFULL;
        unsigned long long ra = a, rb = b;
        #pragma unroll
        for (int s = 1; s <= 4; ++s) {
            ra |= a << s;
            rb |= (b << s) | (a >> (64 - s));
        }
        rb &= 0xFFFFULL;
        ro[r * 3 + 0] = (unsigned int)ra;
        ro[r * 3 + 1] = (unsigned int)(ra >> 32);
        ro[r * 3 + 2] = (unsigned int)rb;
    }
    __syncthreads();
    unsigned int* bmp = BM[wid];
    for (int i = lane; i < DB_H; i += 64) {
        const int lo = (i >= 4) ? i - 4 : 0;
        unsigned int c0 = 0, c1 = 0, c2 = 0;
        for (int ii = lo; ii <= i; ++ii) {
            c0 |= ro[ii * 3 + 0];
            c1 |= ro[ii * 3 + 1];
            c2 |= ro[ii * 3 + 2];
        }
        bmp[i * 3 + 0] = c0; bmp[i * 3 + 1] = c1; bmp[i * 3 + 2] = c2;
    }
    __syncthreads();
    const float* xp = x + plane * DB_PLANE;
    float* op = out + plane * DB_PLANE;
    for (int e = lane; e < DB_PLANE; e += 64) {
        int i = e / DB_W, j = e - i * DB_W;
        unsigned int wb = bmp[i * 3 + (j >> 5)] >> (j & 31);
        op[e] = (wb & 1u) ? 0.0f : xp[e] * scale;
    }
}

extern "C" void kernel_launch(void* const* d_in, const int* in_sizes, int n_in,
                              void* d_out, int out_size, void* d_ws, size_t ws_size,
                              hipStream_t stream) {
    const float* x = (const float*)d_in[0];
    const int* mask = (const int*)d_in[1];
    float* out = (float*)d_out;

    unsigned int* counts = (unsigned int*)d_ws;
    unsigned int* bits = (unsigned int*)((char*)d_ws + DB_CNT_BYTES);
    const size_t bits_bytes = (size_t)DB_NPLANES * DB_PLANE_WORDS * 4;
    const bool use_bits = ws_size >= DB_CNT_BYTES + bits_bytes;

    if (use_bits) {
        db_mask_kernel<<<DB_NPLANES / PPBLK, 256, 0, stream>>>(mask, bits,
                                                               counts);
        db_apply_bits<<<2048, 256, 0, stream>>>(
            (const float4*)x, bits, counts, (float4*)out);
    } else {
        db_count_kernel<<<DB_NPLANES / WPB, 256, 0, stream>>>(mask, counts);
        db_apply_recompute<<<DB_NPLANES / WPB, 256, 0, stream>>>(
            x, mask, counts, out);
    }
}